// Round 5
// baseline (133.144 us; speedup 1.0000x reference)
//
#include <hip/hip_runtime.h>
#include <math.h>

#define GSZ 512
#define NSZ 256
#define NBATCH 8
#define MPTS 131072
#define PI_F 3.14159265358979f
#define BETA_F 13.8551004f
#define BETA2_F (BETA_F * BETA_F)
#define RSQ2 0.70710678f
// LDS pad: +1 float2 every 8 → strided radix-8 writes conflict-free
#define PADIDX(i) ((i) + ((i) >> 3))
#define LUTN 768   // KB-weight LUT intervals over s=u^2 in [0,9]

// ---------------------------------------------------------------- helpers

__device__ __forceinline__ float apod(int i) {
    float x = (float)(i - 128);
    float arg = PI_F * 6.0f * x * (1.0f / 512.0f);
    float t = BETA2_F - arg * arg;
    float st = sqrtf(t);
    return st / sinhf(st);
}

__device__ __forceinline__ float bessi0(float x) {
    float ax = fabsf(x);
    if (ax < 3.75f) {
        float y = ax * (1.0f / 3.75f);
        y *= y;
        return 1.0f + y * (3.5156229f + y * (3.0899424f + y * (1.2067492f
             + y * (0.2659732f + y * (0.0360768f + y * 0.0045813f)))));
    } else {
        float y = 3.75f / ax;
        float p = 0.39894228f + y * (0.01328592f + y * (0.00225319f + y * (-0.00157565f
             + y * (0.00916281f + y * (-0.02057706f + y * (0.02635537f + y * (-0.01647633f
             + y * 0.00392377f)))))));
        return p * __expf(ax) * rsqrtf(ax);
    }
}

// LUT-based KB weight: w(u) = i0(beta*sqrt(1-(u/3)^2)) for u^2<9 else 0.
// Table over s=u^2 (function analytic in s; linear interp err ~2e-4 rel).
__device__ __forceinline__ float kblut(const float* __restrict__ lut, float u) {
    float s = u * u;
    float p = s * ((float)LUTN / 9.0f);
    p = fminf(p, (float)(LUTN - 1));
    int i = (int)p;
    float f = p - (float)i;
    float w = fmaf(f, lut[i + 1] - lut[i], lut[i]);
    return (s < 9.0f) ? w : 0.f;
}

__device__ __forceinline__ float2 cadd(float2 a, float2 b){ return make_float2(a.x+b.x, a.y+b.y); }
__device__ __forceinline__ float2 csub(float2 a, float2 b){ return make_float2(a.x-b.x, a.y-b.y); }
__device__ __forceinline__ float2 cmul(float2 a, float2 b){ return make_float2(a.x*b.x-a.y*b.y, a.x*b.y+a.y*b.x); }
__device__ __forceinline__ float2 mul_negi(float2 a){ return make_float2(a.y, -a.x); }
__device__ __forceinline__ float2 mul_posi(float2 a){ return make_float2(-a.y, a.x); }
__device__ __forceinline__ float2 mul_w81(float2 a){ return make_float2(RSQ2*(a.x+a.y), RSQ2*(a.y-a.x)); }
__device__ __forceinline__ float2 mul_w83(float2 a){ return make_float2(RSQ2*(a.y-a.x), -RSQ2*(a.x+a.y)); }

__device__ __forceinline__ void dft8_combine(float2 E0, float2 E1, float2 E2, float2 E3,
                                             float2 O0, float2 O1, float2 O2, float2 O3,
                                             float2* y) {
    float2 c1 = mul_w81(O1), c2 = mul_negi(O2), c3 = mul_w83(O3);
    y[0] = cadd(E0, O0); y[4] = csub(E0, O0);
    y[1] = cadd(E1, c1); y[5] = csub(E1, c1);
    y[2] = cadd(E2, c2); y[6] = csub(E2, c2);
    y[3] = cadd(E3, c3); y[7] = csub(E3, c3);
}

__device__ __forceinline__ void dft8(const float2* x, float2* y) {
    float2 a0=x[0], a1=x[2], a2=x[4], a3=x[6];
    float2 b0=x[1], b1=x[3], b2=x[5], b3=x[7];
    float2 ta0=cadd(a0,a2), ta1=csub(a0,a2), ta2=cadd(a1,a3), ta3=csub(a1,a3);
    float2 E0=cadd(ta0,ta2), E2=csub(ta0,ta2);
    float2 E1=cadd(ta1, mul_negi(ta3)), E3=cadd(ta1, mul_posi(ta3));
    float2 tb0=cadd(b0,b2), tb1=csub(b0,b2), tb2=cadd(b1,b3), tb3=csub(b1,b3);
    float2 O0=cadd(tb0,tb2), O2=csub(tb0,tb2);
    float2 O1=cadd(tb1, mul_negi(tb3)), O3=cadd(tb1, mul_posi(tb3));
    dft8_combine(E0,E1,E2,E3,O0,O1,O2,O3,y);
}

__device__ __forceinline__ void dft8_pruned(float2 x0, float2 x1, float2 x6, float2 x7, float2* y) {
    float2 E0 = cadd(x0, x6), E2 = csub(x0, x6);
    float2 E1 = cadd(x0, mul_posi(x6)), E3 = cadd(x0, mul_negi(x6));
    float2 O0 = cadd(x1, x7), O2 = csub(x1, x7);
    float2 O1 = cadd(x1, mul_posi(x7)), O3 = cadd(x1, mul_negi(x7));
    dft8_combine(E0,E1,E2,E3,O0,O1,O2,O3,y);
}

template<int S>
__device__ __forceinline__ void twiddle8(int t, float2* y) {
    if (S < 2) {
        int j = (S == 0) ? t : (t >> 3);
        const float scale = (S == 0) ? (-2.0f*PI_F/512.0f) : (-2.0f*PI_F/64.0f);
        float theta = scale * (float)j;
        float sn, cs;
        __sincosf(theta, &sn, &cs);              // sin FIRST, cos second
        float2 w = make_float2(cs, sn), wq = w;
        y[1] = cmul(y[1], wq);
        #pragma unroll
        for (int q = 2; q < 8; ++q) { wq = cmul(wq, w); y[q] = cmul(y[q], wq); }
    }
}

// ---------------------------------------------------------------- pass 1
// Radix-8 row FFT, 4 rows/block. T is COMPACT: only the 256 nonzero rows,
// r' = 4g+r (r'<128 <-> y=r', r'>=128 <-> y=r'+256).
__global__ __launch_bounds__(256) void pass1_rowfft(const float* __restrict__ image,
                                                    float2* __restrict__ T) {
    __shared__ float2 sm[2][4][578];
    int tid = threadIdx.x;
    int r = tid >> 6, t = tid & 63;
    int blk = blockIdx.x;
    int b = blk & 7;
    int g = blk >> 3;                               // 0..63
    int rp = (g << 2) + r;                          // compact row 0..255
    int y = (rp < 128) ? rp : (rp + 256);
    int iy = (y < 128) ? (y + 128) : (y - 384);
    float ay = apod(iy);
    const float* irow = image + ((size_t)(b * NSZ + iy)) * NSZ;

    float2 y8[8];
    {
        int ix0 = t + 128, ix1 = t + 192, ix6 = t, ix7 = t + 64;
        float2 x0 = make_float2(irow[ix0] * ay * apod(ix0), 0.f);
        float2 x1 = make_float2(irow[ix1] * ay * apod(ix1), 0.f);
        float2 x6 = make_float2(irow[ix6] * ay * apod(ix6), 0.f);
        float2 x7 = make_float2(irow[ix7] * ay * apod(ix7), 0.f);
        dft8_pruned(x0, x1, x6, x7, y8);
        twiddle8<0>(t, y8);
    }
    float2* A  = sm[0][r];
    float2* Bf = sm[1][r];
    #pragma unroll
    for (int q = 0; q < 8; ++q) A[PADIDX((t << 3) + q)] = y8[q];
    __syncthreads();
    {
        float2 x[8];
        #pragma unroll
        for (int p = 0; p < 8; ++p) x[p] = A[PADIDX(t + (p << 6))];
        dft8(x, y8);
        twiddle8<1>(t, y8);
        int j = t >> 3, k = t & 7, base = k + (j << 6);
        #pragma unroll
        for (int q = 0; q < 8; ++q) Bf[PADIDX(base + (q << 3))] = y8[q];
    }
    __syncthreads();
    {
        float2 x[8];
        #pragma unroll
        for (int p = 0; p < 8; ++p) x[p] = Bf[PADIDX(t + (p << 6))];
        dft8(x, y8);
        float2* Trow = T + (((size_t)(b << 8) + rp) << 9);
        #pragma unroll
        for (int q = 0; q < 8; ++q) Trow[t + (q << 6)] = y8[q];
    }
}

// ---------------------------------------------------------------- pass 2
// Radix-8 column FFT, 8 cols/block, single LDS buffer (in-place Stockham
// with a barrier between each stage's read and write). Global load/store
// phases touch full 64B lines (8 cols x 8B). T is compact 256-row; pruned
// stage 0 taps at compact rows {t, t+64, t+128, t+192} = grid rows
// {t, t+64, t+384, t+448}.
__global__ __launch_bounds__(256) void pass2_colfft(const float2* __restrict__ T,
                                                    float2* __restrict__ kgrid) {
    __shared__ float2 B[8][578];
    int tid = threadIdx.x;
    int blk = blockIdx.x;
    int b = blk & 7;
    int colbase = (blk >> 3) << 3;                  // 0..504 step 8
    const float2* Tb = T + ((size_t)b << 17);       // 256*512 per batch
    float2* Kb = kgrid + ((size_t)b << 18);

    { // load: 256 compact rows x 8 cols, 64B per 8-lane group
        int c = tid & 7, r0 = tid >> 3;             // r0 0..31
        #pragma unroll
        for (int k = 0; k < 8; ++k) {
            int rr = r0 + (k << 5);
            B[c][PADIDX(rr)] = Tb[((size_t)rr << 9) + colbase + c];
        }
    }
    __syncthreads();
    int t = tid & 63;
    int c0 = tid >> 6;                              // cols c0 and c0+4
    float2 ya[8], yb[8];
    // ---- stage 0 (pruned), read
    {
        float2* Ba = B[c0];
        float2* Bb = B[c0 + 4];
        float2 a0 = Ba[PADIDX(t)],   a1 = Ba[PADIDX(t + 64)];
        float2 a6 = Ba[PADIDX(t + 128)], a7 = Ba[PADIDX(t + 192)];
        float2 b0 = Bb[PADIDX(t)],   b1 = Bb[PADIDX(t + 64)];
        float2 b6 = Bb[PADIDX(t + 128)], b7 = Bb[PADIDX(t + 192)];
        dft8_pruned(a0, a1, a6, a7, ya); twiddle8<0>(t, ya);
        dft8_pruned(b0, b1, b6, b7, yb); twiddle8<0>(t, yb);
    }
    __syncthreads();
    #pragma unroll
    for (int q = 0; q < 8; ++q) {
        B[c0][PADIDX((t << 3) + q)]     = ya[q];
        B[c0 + 4][PADIDX((t << 3) + q)] = yb[q];
    }
    __syncthreads();
    // ---- stage 1
    {
        float2 xa[8], xb[8];
        #pragma unroll
        for (int p = 0; p < 8; ++p) { xa[p] = B[c0][PADIDX(t + (p << 6))]; xb[p] = B[c0 + 4][PADIDX(t + (p << 6))]; }
        dft8(xa, ya); twiddle8<1>(t, ya);
        dft8(xb, yb); twiddle8<1>(t, yb);
    }
    __syncthreads();
    {
        int j = t >> 3, k = t & 7, base = k + (j << 6);
        #pragma unroll
        for (int q = 0; q < 8; ++q) {
            B[c0][PADIDX(base + (q << 3))]     = ya[q];
            B[c0 + 4][PADIDX(base + (q << 3))] = yb[q];
        }
    }
    __syncthreads();
    // ---- stage 2 (no twiddle), natural order out
    {
        float2 xa[8], xb[8];
        #pragma unroll
        for (int p = 0; p < 8; ++p) { xa[p] = B[c0][PADIDX(t + (p << 6))]; xb[p] = B[c0 + 4][PADIDX(t + (p << 6))]; }
        dft8(xa, ya);
        dft8(xb, yb);
    }
    __syncthreads();
    #pragma unroll
    for (int q = 0; q < 8; ++q) {
        B[c0][PADIDX(t + (q << 6))]     = ya[q];
        B[c0 + 4][PADIDX(t + (q << 6))] = yb[q];
    }
    __syncthreads();
    { // store: 512 rows x 8 cols, full lines
        int c = tid & 7, r0 = tid >> 3;
        #pragma unroll
        for (int k = 0; k < 16; ++k) {
            int rr = r0 + (k << 5);
            Kb[((size_t)rr << 9) + colbase + c] = B[c][PADIDX(rr)];
        }
    }
}

// ---------------------------------------------------------------- pass 3
// Wave-cooperative KB gather, 8 lanes/point, weights via LDS LUT.
// Grid-strided: 256 blocks/batch, 512 points/block (amortizes LUT fill).
__global__ __launch_bounds__(256) void interp_kb(const float* __restrict__ ktraj,
                                                 const float* __restrict__ dcf,
                                                 const float2* __restrict__ kgrid,
                                                 float* __restrict__ out) {
    __shared__ float lut[LUTN + 1];
    int tid = threadIdx.x;
    for (int i = tid; i <= LUTN; i += 256) {
        float s = (float)i * (9.0f / (float)LUTN);
        float tt = fmaxf(1.0f - s * (1.0f / 9.0f), 0.f);
        lut[i] = bessi0(BETA_F * sqrtf(tt));
    }
    __syncthreads();

    int blk = blockIdx.x;
    int b = blk & 7;                          // XCD affinity
    int gb = blk >> 3;                        // 0..255
    int j = tid & 7;                          // lane within 8-lane group
    int gloc = tid >> 3;                      // group in block 0..31
    int lane = tid & 63;
    int gbase = lane & 56;

    const float SCALE = (float)GSZ / (2.0f * PI_F);
    const float2* Kb = kgrid + ((size_t)b << 18);
    const float* kt1 = ktraj + ((size_t)(b * 2)) * MPTS;
    const float* kt2 = kt1 + MPTS;
    const float* dcfb = dcf + ((size_t)b << 17);
    float* out_re = out + ((size_t)b << 17);
    float* out_im = out_re + (size_t)NBATCH * MPTS;

    int m0 = (gb << 9) + gloc;                // block covers [gb*512, gb*512+512)
    #pragma unroll 2
    for (int it = 0; it < 16; ++it) {
        int m = m0 + (it << 5);
        float tm1 = kt1[m] * SCALE;
        float tm2 = kt2[m] * SCALE;
        float f1 = floorf(tm1), f2 = floorf(tm2);
        int if1 = (int)f1, if2 = (int)f2;

        float w2_own = kblut(lut, tm2 - f2 - (float)(j - 2));
        int   i2_own = (if2 + j - 2) & 511;
        float w1_own = kblut(lut, tm1 - f1 - (float)(j - 2));

        float s_re = 0.f, s_im = 0.f;
        #pragma unroll
        for (int a = 0; a < 6; ++a) {
            int i1a = (if1 + a - 2) & 511;
            float w1a = __shfl(w1_own, gbase + a, 64);
            float2 v = Kb[((size_t)i1a << 9) + i2_own];
            s_re = fmaf(w1a, v.x, s_re);
            s_im = fmaf(w1a, v.y, s_im);
        }
        float p_re = w2_own * s_re;
        float p_im = w2_own * s_im;
        #pragma unroll
        for (int d = 1; d < 8; d <<= 1) {
            p_re += __shfl_xor(p_re, d, 64);
            p_im += __shfl_xor(p_im, d, 64);
        }
        float dd = dcfb[m];
        if (j == 0) out_re[m] = p_re * dd;
        if (j == 1) out_im[m] = p_im * dd;
    }
}

// ---------------------------------------------------------------- launch

extern "C" void kernel_launch(void* const* d_in, const int* in_sizes, int n_in,
                              void* d_out, int out_size, void* d_ws, size_t ws_size,
                              hipStream_t stream) {
    const float* image = (const float*)d_in[0];   // (8,256,256) f32
    const float* ktraj = (const float*)d_in[1];   // (8,2,131072) f32
    const float* dcf   = (const float*)d_in[2];   // (8,131072) f32
    float* out = (float*)d_out;                   // (2,8,131072) f32

    float2* T     = (float2*)d_ws;                        // 8*256*512 c64 = 8.4 MB
    float2* kgrid = T + (size_t)NBATCH * 256 * GSZ;       // 8*512*512 c64 = 16.8 MB

    pass1_rowfft<<<NBATCH * 64, 256, 0, stream>>>(image, T);    // 256 rows / 4 per block
    pass2_colfft<<<NBATCH * 64, 256, 0, stream>>>(T, kgrid);    // 512 cols / 8 per block
    interp_kb<<<NBATCH * 256, 256, 0, stream>>>(ktraj, dcf, kgrid, out);
}